// Round 6
// baseline (113.759 us; speedup 1.0000x reference)
//
#include <hip/hip_runtime.h>
#include <math.h>

// LocalAttention: B=2, T=2048, C=512, WINDOW=32
#define BB 2
#define TT 2048
#define CC 512
#define WIN 32
#define WSZ 63            // 2*WIN-1
#define MM (BB * TT)      // 4096

typedef __attribute__((ext_vector_type(8))) short short8;
typedef __attribute__((ext_vector_type(4))) float floatx4;

__device__ inline unsigned short bf16_rn(float f) {
  unsigned u = __builtin_bit_cast(unsigned, f);
  u += 0x7fff + ((u >> 16) & 1);
  return (unsigned short)(u >> 16);
}
__device__ inline unsigned pack_bf16x2(float lo, float hi) {
  return (unsigned)bf16_rn(lo) | ((unsigned)bf16_rn(hi) << 16);
}

// ---------------------------------------------------------------------------
// Pre-convert fp32 inputs -> bf16 (x, w_qkv, w_proj). 8 elems/thread.
// NOTE (R4 lesson): keep this stage. Steady-state kernels must consume ws
// copies refreshed every call, not d_in directly — the replay-invariance
// check diverged when gemms read fp32 inputs in the timed phase.
// ---------------------------------------------------------------------------
#define NX  (MM * CC)          // 2097152
#define NWQ (3 * CC * CC)      // 786432
#define NWP (CC * CC)          // 262144

__global__ __launch_bounds__(256) void convert_bf16(
    const float* __restrict__ x, const float* __restrict__ wq,
    const float* __restrict__ wp, ushort* __restrict__ xb,
    ushort* __restrict__ wqb, ushort* __restrict__ wpb) {
  const size_t e = ((size_t)blockIdx.x * 256 + threadIdx.x) * 8;
  const float* src;
  ushort* dst;
  size_t off;
  if (e < NX) { src = x; dst = xb; off = e; }
  else if (e < NX + NWQ) { src = wq; dst = wqb; off = e - NX; }
  else { src = wp; dst = wpb; off = e - NX - NWQ; }
  float4 v0 = ((const float4*)(src + off))[0];
  float4 v1 = ((const float4*)(src + off))[1];
  uint4 o;
  o.x = pack_bf16x2(v0.x, v0.y);
  o.y = pack_bf16x2(v0.z, v0.w);
  o.z = pack_bf16x2(v1.x, v1.y);
  o.w = pack_bf16x2(v1.z, v1.w);
  *(uint4*)(dst + off) = o;
}

// ---------------------------------------------------------------------------
// Barrier-light NT GEMM: C[m,n] = sum_k A[m,k]*B[n,k] + bias[n], K=512 fixed.
// Block = BM x 64. B-panel (64 n x 256 k) staged in LDS once per k-half ->
// only 3 barriers per block, NO per-K-step barrier/drain. A fragments are
// loaded directly from global (L1/L2-hot). 4 waves, each owns BM/4 m-rows
// and the full 64-n range.
// V path (VT != nullptr && n0 >= 1024): tile is bias-added, packed to bf16,
// transposed through LDS, and written as coalesced 256B rows of VT[n][m].
// ---------------------------------------------------------------------------
#define PSTR 264   // B-panel k-stride (elems); 528B rows -> 2-way banked frag reads
#define VSTR 136   // V-transpose m-stride (elems); 16B-aligned rows, odd granules

template <int BM, typename OT>
__global__ __launch_bounds__(256) void gemm_panel(
    const ushort* __restrict__ A, const ushort* __restrict__ B,
    const float* __restrict__ bias, OT* __restrict__ C,
    ushort* __restrict__ VT, int M, int N) {
  constexpr int MIW = BM / 64;                    // m-frags per wave (2 or 1)
  __shared__ __align__(16) ushort Bs[64 * PSTR];  // 33792 B; Vt aliases below

  const int tid = threadIdx.x;
  const int lane = tid & 63;
  const int wave = tid >> 6;
  const int m0 = blockIdx.y * BM;
  const int n0 = blockIdx.x * 64;
  const int wm = wave * (BM / 4);
  const int mlane = lane & 15, quad = lane >> 4;

  floatx4 acc[MIW][4];
#pragma unroll
  for (int i = 0; i < MIW; ++i)
#pragma unroll
    for (int j = 0; j < 4; ++j) acc[i][j] = (floatx4){0.f, 0.f, 0.f, 0.f};

  for (int h = 0; h < 2; ++h) {
    if (h) __syncthreads();
    // stage B panel half: 64 rows x 256 k = 2048 uint4, coalesced
#pragma unroll
    for (int i = 0; i < 8; ++i) {
      const int idx = tid + 256 * i;
      const int r = idx >> 5, kc = (idx & 31) * 8;
      *(uint4*)(&Bs[r * PSTR + kc]) =
          *(const uint4*)(B + (size_t)(n0 + r) * CC + h * 256 + kc);
    }
    __syncthreads();
#pragma unroll
    for (int ks = 0; ks < 8; ++ks) {
      short8 bfr[4];
#pragma unroll
      for (int ni = 0; ni < 4; ++ni)
        bfr[ni] = *(const short8*)(&Bs[(ni * 16 + mlane) * PSTR + ks * 32 + quad * 8]);
#pragma unroll
      for (int mi = 0; mi < MIW; ++mi) {
        short8 af = *(const short8*)(
            A + (size_t)(m0 + wm + mi * 16 + mlane) * CC + h * 256 + ks * 32 + quad * 8);
#pragma unroll
        for (int ni = 0; ni < 4; ++ni)
          acc[mi][ni] = __builtin_amdgcn_mfma_f32_16x16x32_bf16(af, bfr[ni], acc[mi][ni], 0, 0, 0);
      }
    }
  }

  // epilogue: D row = quad*4 + r (m), col = mlane (n)
  const bool vpath = (VT != nullptr) && (n0 >= 1024);
  if (!vpath) {
#pragma unroll
    for (int ni = 0; ni < 4; ++ni) {
      const int n = n0 + ni * 16 + mlane;
      const float bn = bias[n];
#pragma unroll
      for (int mi = 0; mi < MIW; ++mi) {
        const int mbase = m0 + wm + mi * 16 + quad * 4;
#pragma unroll
        for (int r = 0; r < 4; ++r) {
          float val = acc[mi][ni][r] + bn;
          if constexpr (sizeof(OT) == 2)
            ((ushort*)C)[(size_t)(mbase + r) * N + n] = bf16_rn(val);
          else
            ((float*)C)[(size_t)(mbase + r) * N + n] = val;
        }
      }
    }
  } else if constexpr (BM == 128) {
    // transpose through LDS, then coalesced VT[n][m] row writes
    ushort* Vt = Bs;  // alias; 64 x VSTR = 17408 B
    __syncthreads();
#pragma unroll
    for (int ni = 0; ni < 4; ++ni) {
      const int n_l = ni * 16 + mlane;
      const float bn = bias[n0 + n_l];
#pragma unroll
      for (int mi = 0; mi < MIW; ++mi) {
        const int m_l = wm + mi * 16 + quad * 4;
        ushort4 pk;
        pk.x = bf16_rn(acc[mi][ni][0] + bn);
        pk.y = bf16_rn(acc[mi][ni][1] + bn);
        pk.z = bf16_rn(acc[mi][ni][2] + bn);
        pk.w = bf16_rn(acc[mi][ni][3] + bn);
        *(ushort4*)(&Vt[n_l * VSTR + m_l]) = pk;
      }
    }
    __syncthreads();
#pragma unroll
    for (int i = 0; i < 4; ++i) {  // 64 rows x 16 uint4
      const int idx = tid + 256 * i;
      const int n_l = idx >> 4, mo = (idx & 15) * 8;
      *(uint4*)(VT + (size_t)(n0 - 1024 + n_l) * M + m0 + mo) =
          *(const uint4*)(&Vt[n_l * VSTR + mo]);
    }
  }
}

// ---------------------------------------------------------------------------
// LDS-free MFMA banded attention. 512-thread blocks, TWO adjacent 16-token
// tiles per block (wave group g = tid>>8 runs tile t0+16g with the exact
// single-tile code). Why: at 256x256 this kernel was 1 wave/SIMD — zero TLP,
// all global-load latency exposed (R5's tiny P-hoist bought 1.8us -> latency-
// dominated). 8 waves/block -> 2 waves/SIMD, and the paired tiles' K-bands
// overlap 64/80 rows (vT windows 64/80 cols) -> second half runs L1/L2-hot.
// Grid 128, XCD-bijective swizzle (16 contiguous blocks per XCD).
// No 32-token block spans the batch boundary (2048%32==0).
// OOB reads fault-safe via ws guards; garbage lands in masked/P=0 positions.
// ---------------------------------------------------------------------------
#define ATILE 16
#define SLD 84    // S row stride (floats)
#define PLD 104   // P row stride (ushorts), odd granules -> conflict-free

__global__ __launch_bounds__(512) void attn_mfma(
    const ushort* __restrict__ qkv, const ushort* __restrict__ vT,
    ushort* __restrict__ out) {
  __shared__ __align__(16) float s_s[2][16 * SLD];
  __shared__ __align__(16) ushort p_s[2][16 * PLD];

  const int tid = threadIdx.x;
  const int g = tid >> 8;           // tile half within block
  const int wl = (tid >> 6) & 3;    // wave index within half (0..3)
  const int lane = tid & 63;
  const int mlane = lane & 15, quad = lane >> 4;
  // XCD-bijective swizzle: 128 blocks, 8 XCDs, 16 blocks each (contiguous)
  const int blk = ((blockIdx.x & 7) << 4) | (blockIdx.x >> 3);
  const int bt0 = blk * 32 + g * ATILE;
  const int b = bt0 / TT, t0 = bt0 % TT;
  const ushort* qbase = qkv + (size_t)b * TT * (3 * CC);

  const ushort* qrow  = qbase + (ptrdiff_t)(t0 + mlane) * (3 * CC);
  const ushort* krow0 = qbase + (ptrdiff_t)(t0 - 32 + wl * 16 + mlane) * (3 * CC) + CC;
  const ushort* krow1 = qbase + (ptrdiff_t)(t0 - 32 + 64 + mlane) * (3 * CC) + CC;
  floatx4 sacc0 = (floatx4){0.f, 0.f, 0.f, 0.f};
  floatx4 sacc1 = (floatx4){0.f, 0.f, 0.f, 0.f};
#pragma unroll
  for (int ks = 0; ks < 16; ++ks) {
    short8 a  = *(const short8*)(qrow + ks * 32 + quad * 8);
    short8 b0 = *(const short8*)(krow0 + ks * 32 + quad * 8);
    sacc0 = __builtin_amdgcn_mfma_f32_16x16x32_bf16(a, b0, sacc0, 0, 0, 0);
    if (wl == 0) {
      short8 b1 = *(const short8*)(krow1 + ks * 32 + quad * 8);
      sacc1 = __builtin_amdgcn_mfma_f32_16x16x32_bf16(a, b1, sacc1, 0, 0, 0);
    }
  }

#pragma unroll
  for (int r = 0; r < 4; ++r)
    s_s[g][(quad * 4 + r) * SLD + wl * 16 + mlane] = sacc0[r];
  if (wl == 0) {
#pragma unroll
    for (int r = 0; r < 4; ++r)
      s_s[g][(quad * 4 + r) * SLD + 64 + mlane] = sacc1[r];
  }
  __syncthreads();

  {
    const int row = (tid >> 4) & 15, li = tid & 15;
    const float inv_scale = 0.044194173824159216f;  // 512^-0.5
    float e[5];
    float mx = -INFINITY;
#pragma unroll
    for (int i = 0; i < 5; ++i) {
      const int r = li + 16 * i;
      const int j = r - 1 - row;
      const int src = t0 - 32 + r;
      const bool valid = (j >= 0) && (j < WSZ) && (src >= 0) && (src < TT);
      e[i] = valid ? s_s[g][row * SLD + r] * inv_scale : -INFINITY;
      mx = fmaxf(mx, e[i]);
    }
    mx = fmaxf(mx, __shfl_xor(mx, 1)); mx = fmaxf(mx, __shfl_xor(mx, 2));
    mx = fmaxf(mx, __shfl_xor(mx, 4)); mx = fmaxf(mx, __shfl_xor(mx, 8));
    float sum = 0.f;
#pragma unroll
    for (int i = 0; i < 5; ++i) {
      e[i] = (e[i] == -INFINITY) ? 0.f : __expf(e[i] - mx);
      sum += e[i];
    }
    sum += __shfl_xor(sum, 1); sum += __shfl_xor(sum, 2);
    sum += __shfl_xor(sum, 4); sum += __shfl_xor(sum, 8);
    const float rs = 1.f / sum;
#pragma unroll
    for (int i = 0; i < 5; ++i)
      p_s[g][row * PLD + li + 16 * i] = bf16_rn(e[i] * rs);
    if (li < 8) {
      p_s[g][row * PLD + 80 + li] = 0;
      p_s[g][row * PLD + 88 + li] = 0;
      p_s[g][row * PLD + 96 + li] = 0;
    }
  }
  __syncthreads();

  // P fragments are nt8-invariant: hoist the 3 LDS reads out of the PV loop.
  short8 pa[3];
#pragma unroll
  for (int ks = 0; ks < 3; ++ks)
    pa[ks] = *(const short8*)(&p_s[g][mlane * PLD + ks * 32 + quad * 8]);

  const ptrdiff_t mcol0 = (ptrdiff_t)b * TT + t0 - 32;
#pragma unroll 2
  for (int nt8 = 0; nt8 < 8; ++nt8) {
    const int nt = wl * 8 + nt8;
    const ushort* vrow = vT + (ptrdiff_t)(nt * 16 + mlane) * MM + mcol0;
    floatx4 o = (floatx4){0.f, 0.f, 0.f, 0.f};
#pragma unroll
    for (int ks = 0; ks < 3; ++ks) {
      short8 bv = *(const short8*)(vrow + ks * 32 + quad * 8);
      o = __builtin_amdgcn_mfma_f32_16x16x32_bf16(pa[ks], bv, o, 0, 0, 0);
    }
#pragma unroll
    for (int r = 0; r < 4; ++r)
      out[(size_t)(bt0 + quad * 4 + r) * CC + nt * 16 + mlane] = bf16_rn(o[r]);
  }
}

// ---------------------------------------------------------------------------
extern "C" void kernel_launch(void* const* d_in, const int* in_sizes, int n_in,
                              void* d_out, int out_size, void* d_ws, size_t ws_size,
                              hipStream_t stream) {
  const float* x      = (const float*)d_in[0];
  const float* w_qkv  = (const float*)d_in[1];
  const float* b_qkv  = (const float*)d_in[2];
  const float* w_proj = (const float*)d_in[3];
  const float* b_proj = (const float*)d_in[4];
  float* outp = (float*)d_out;

  // ws layout (ushorts). 256 KB front guard absorbs attn's src<0 K-reads;
  // attn buffer right after qkv absorbs src>=TT K-read overruns.
  ushort* base  = (ushort*)d_ws;
  ushort* qkv   = base + 131072;                   // MM x 1536 (V third unused)
  ushort* attn  = qkv + (size_t)MM * 3 * CC;       // MM x 512
  ushort* xb    = attn + (size_t)MM * CC;          // MM x 512
  ushort* wqb   = xb + (size_t)NX;                 // 1536 x 512
  ushort* wpb   = wqb + (size_t)NWQ;               // 512 x 512
  ushort* vTg   = wpb + (size_t)NWP;               // guard(64) + 512 x 4096 + guard(64)
  ushort* vT    = vTg + 64;

  // 0) convert fp32 inputs to bf16
  convert_bf16<<<(NX + NWQ + NWP) / (256 * 8), 256, 0, stream>>>(x, w_qkv, w_proj, xb, wqb, wpb);
  // 1) qkv = x @ w_qkv.T + b_qkv -> Q,K bf16 rows; V written transposed to vT
  {
    dim3 grid((3 * CC) / 64, MM / 128);  // 24 x 32 = 768 blocks
    gemm_panel<128, ushort><<<grid, 256, 0, stream>>>(xb, wqb, b_qkv, qkv, vT, MM, 3 * CC);
  }
  // 2) banded attention: 128 blocks x 512 threads, 2 tiles/block (2 waves/SIMD)
  attn_mfma<<<MM / (2 * ATILE), 512, 0, stream>>>(qkv, vT, attn);
  // 3) out = attn @ w_proj.T + b_proj -> fp32
  {
    dim3 grid(CC / 64, MM / 64);  // 8 x 64 = 512 blocks
    gemm_panel<64, float><<<grid, 256, 0, stream>>>(attn, wpb, b_proj, outp, nullptr, MM, CC);
  }
}

// Round 7
// 112.246 us; speedup vs baseline: 1.0135x; 1.0135x over previous
//
#include <hip/hip_runtime.h>
#include <math.h>

// LocalAttention: B=2, T=2048, C=512, WINDOW=32
#define BB 2
#define TT 2048
#define CC 512
#define WIN 32
#define WSZ 63            // 2*WIN-1
#define MM (BB * TT)      // 4096

typedef __attribute__((ext_vector_type(8))) short short8;
typedef __attribute__((ext_vector_type(4))) float floatx4;

__device__ inline unsigned short bf16_rn(float f) {
  unsigned u = __builtin_bit_cast(unsigned, f);
  u += 0x7fff + ((u >> 16) & 1);
  return (unsigned short)(u >> 16);
}
__device__ inline unsigned pack_bf16x2(float lo, float hi) {
  return (unsigned)bf16_rn(lo) | ((unsigned)bf16_rn(hi) << 16);
}

// ---------------------------------------------------------------------------
// PACKET-TILED LAYOUTS (this round's change). Every MFMA fragment load used
// to gather 16 rows x 16B at 1-8KB stride = 16 L2 lines / wave instruction.
// New layouts make each 16-lane fragment read ONE contiguous 256B region:
//   A-type  [mt=m/16][kp=k/8][m&15][k&7]   (xb, Q, K, attn-out; 8192/tile)
//   B-type  [np=n/64][kp=k/8][n&63][k&7]   (w_qkv, w_proj; 32768/panel)
//   V-type  [nt=n/16][mp=m/8][n&15][m&7]   (vT; 65536/nt-slab)
// Writers only change addresses (scatter stores either way); readers go from
// 16 lines -> 1 line. Op order identical everywhere -> bit-identical output.
// ---------------------------------------------------------------------------
#define NX  (MM * CC)          // 2097152
#define NWQ (3 * CC * CC)      // 786432
#define NWP (CC * CC)          // 262144

// Pre-convert fp32 -> bf16 into tiled ws buffers. One 8-elem packet/thread.
// (R4 lesson: keep this stage; steady-state kernels read only ws copies.)
__global__ __launch_bounds__(256) void convert_bf16(
    const float* __restrict__ x, const float* __restrict__ wq,
    const float* __restrict__ wp, ushort* __restrict__ xb,
    ushort* __restrict__ wqb, ushort* __restrict__ wpb) {
  const size_t e = ((size_t)blockIdx.x * 256 + threadIdx.x) * 8;
  const float* src;
  ushort* dst;
  size_t off;
  if (e < NX) {
    const size_t m = e >> 9, k = e & 511;
    src = x + e; dst = xb;
    off = (m >> 4) * 8192 + (k >> 3) * 128 + (m & 15) * 8;
  } else if (e < NX + NWQ) {
    const size_t i = e - NX, n = i >> 9, k = i & 511;
    src = wq + i; dst = wqb;
    off = (n >> 6) * 32768 + (k >> 3) * 512 + (n & 63) * 8;
  } else {
    const size_t i = e - NX - NWQ, n = i >> 9, k = i & 511;
    src = wp + i; dst = wpb;
    off = (n >> 6) * 32768 + (k >> 3) * 512 + (n & 63) * 8;
  }
  float4 v0 = ((const float4*)src)[0];
  float4 v1 = ((const float4*)src)[1];
  uint4 o;
  o.x = pack_bf16x2(v0.x, v0.y);
  o.y = pack_bf16x2(v0.z, v0.w);
  o.z = pack_bf16x2(v1.x, v1.y);
  o.w = pack_bf16x2(v1.z, v1.w);
  *(uint4*)(dst + off) = o;
}

// ---------------------------------------------------------------------------
// Barrier-light NT GEMM on tiled layouts. Block = BM x 64, K=512 fixed.
// B-panel half (64n x 256k) = one CONTIGUOUS 32KB chunk -> linear LDS copy,
// fully coalesced; fragment reads contiguous 256B/group (min bank aliasing).
// A fragments direct from global, 1 line per 16-lane group.
// gemm1 (OT=ushort): n0<512 -> Q tiles, <1024 -> K tiles (Kb = C + 2M elems),
//   >=1024 -> V written DIRECTLY to tiled vT via ushort4 (no LDS transpose,
//   no extra barriers). gemm2 (OT=float): row-major fp32 final out.
// ---------------------------------------------------------------------------
template <int BM, typename OT>
__global__ __launch_bounds__(256) void gemm_panel(
    const ushort* __restrict__ A, const ushort* __restrict__ Bt,
    const float* __restrict__ bias, OT* __restrict__ C,
    ushort* __restrict__ VT, int N) {
  constexpr int MIW = BM / 64;                  // m-frags per wave (2 or 1)
  __shared__ __align__(16) ushort Bs[16384];    // 32 KB, linear

  const int tid = threadIdx.x;
  const int lane = tid & 63;
  const int wave = tid >> 6;
  const int m0 = blockIdx.y * BM;
  const int n0 = blockIdx.x * 64;
  const int wm = wave * (BM / 4);
  const int mlane = lane & 15, quad = lane >> 4;

  floatx4 acc[MIW][4];
#pragma unroll
  for (int i = 0; i < MIW; ++i)
#pragma unroll
    for (int j = 0; j < 4; ++j) acc[i][j] = (floatx4){0.f, 0.f, 0.f, 0.f};

  const ushort* bpanel = Bt + (size_t)(n0 >> 6) * 32768;
  for (int h = 0; h < 2; ++h) {
    if (h) __syncthreads();
    // stage B panel half: contiguous 32KB, 8 x uint4 per thread
#pragma unroll
    for (int i = 0; i < 8; ++i) {
      const int idx = tid + 256 * i;
      *(uint4*)(&Bs[idx * 8]) = *(const uint4*)(bpanel + h * 16384 + idx * 8);
    }
    __syncthreads();
#pragma unroll
    for (int ks = 0; ks < 8; ++ks) {
      short8 bfr[4];
#pragma unroll
      for (int ni = 0; ni < 4; ++ni)
        bfr[ni] = *(const short8*)(&Bs[((ks * 4 + quad) * 64 + ni * 16 + mlane) * 8]);
#pragma unroll
      for (int mi = 0; mi < MIW; ++mi) {
        const size_t aoff = (size_t)((m0 + wm) / 16 + mi) * 8192 +
                            (size_t)(h * 32 + ks * 4 + quad) * 128 + mlane * 8;
        short8 af = *(const short8*)(A + aoff);
#pragma unroll
        for (int ni = 0; ni < 4; ++ni)
          acc[mi][ni] = __builtin_amdgcn_mfma_f32_16x16x32_bf16(af, bfr[ni], acc[mi][ni], 0, 0, 0);
      }
    }
  }

  // epilogues. D row = quad*4 + r (m), col = mlane (n)
  if constexpr (sizeof(OT) == 2) {
    if (n0 < 1024) {
      // Q (n<512) / K (512..1023) tiled A-type writes
      ushort* dst = (ushort*)C + (n0 < 512 ? 0 : 2097152);
      const int c0 = n0 & 511;
#pragma unroll
      for (int ni = 0; ni < 4; ++ni) {
        const int c = c0 + ni * 16 + mlane;
        const float bn = bias[n0 + ni * 16 + mlane];
        const int kpo = (c >> 3) * 128 + (c & 7);
#pragma unroll
        for (int mi = 0; mi < MIW; ++mi) {
          const size_t mb =
              (size_t)((m0 + wm) / 16 + mi) * 8192 + kpo + (size_t)quad * 32;
#pragma unroll
          for (int r = 0; r < 4; ++r)
            dst[mb + r * 8] = bf16_rn(acc[mi][ni][r] + bn);
        }
      }
    } else {
      // V: direct tiled-vT ushort4 stores (2 x 256B regions per instr)
#pragma unroll
      for (int ni = 0; ni < 4; ++ni) {
        const int nv = (n0 - 1024) + ni * 16 + mlane;
        const float bn = bias[n0 + ni * 16 + mlane];
#pragma unroll
        for (int mi = 0; mi < MIW; ++mi) {
          const int mb = m0 + wm + mi * 16 + quad * 4;
          ushort4 pk;
          pk.x = bf16_rn(acc[mi][ni][0] + bn);
          pk.y = bf16_rn(acc[mi][ni][1] + bn);
          pk.z = bf16_rn(acc[mi][ni][2] + bn);
          pk.w = bf16_rn(acc[mi][ni][3] + bn);
          *(ushort4*)(&VT[(size_t)(nv >> 4) * 65536 + (size_t)(mb >> 3) * 128 +
                          (nv & 15) * 8 + (mb & 7)]) = pk;
        }
      }
    }
  } else {
    // final fp32 row-major out
#pragma unroll
    for (int ni = 0; ni < 4; ++ni) {
      const int n = n0 + ni * 16 + mlane;
      const float bn = bias[n];
#pragma unroll
      for (int mi = 0; mi < MIW; ++mi) {
        const int mbase = m0 + wm + mi * 16 + quad * 4;
#pragma unroll
        for (int r = 0; r < 4; ++r)
          ((float*)C)[(size_t)(mbase + r) * N + n] = acc[mi][ni][r] + bn;
      }
    }
  }
}

// ---------------------------------------------------------------------------
// LDS-free MFMA banded attention on tiled layouts. Block = 16 tokens, grid
// 256 = 1 block/CU (R6 lesson: keep all CUs, short per-block path), XCD-
// bijective swizzle. Q/K/vT fragment loads are contiguous 256B per 16-lane
// group (1 line, was 16). Output written tiled for gemm2's A-reads.
// OOB K tiles land in Qb-tail / attn_t (garbage -> masked); OOB vT tiles in
// +-1024-elem guards (garbage x P=0).
// ---------------------------------------------------------------------------
#define SLD 84    // S row stride (floats)
#define PLD 104   // P row stride (ushorts), odd granules -> conflict-free

__global__ __launch_bounds__(256) void attn_mfma(
    const ushort* __restrict__ Qb, const ushort* __restrict__ Kb,
    const ushort* __restrict__ VT, ushort* __restrict__ outT) {
  __shared__ __align__(16) float s_s[16 * SLD];
  __shared__ __align__(16) ushort p_s[16 * PLD];

  const int tid = threadIdx.x;
  const int wave = tid >> 6, lane = tid & 63;
  const int mlane = lane & 15, quad = lane >> 4;
  // XCD-bijective swizzle: 256 blocks, 8 XCDs, 32 tiles each (contiguous)
  const int tile = ((blockIdx.x & 7) << 5) | (blockIdx.x >> 3);
  const int bt0 = tile * 16;          // global token base
  const int t0 = bt0 % TT;            // within-batch (for masking)

  // ---- QK^T over the 80-key band (tiles tile-2 .. tile+2)
  const ushort* qp  = Qb + (size_t)tile * 8192 + quad * 128 + mlane * 8;
  const ushort* kp0 = Kb + (ptrdiff_t)(tile - 2 + wave) * 8192 + quad * 128 + mlane * 8;
  const ushort* kp1 = Kb + (ptrdiff_t)(tile + 2) * 8192 + quad * 128 + mlane * 8;
  floatx4 sacc0 = (floatx4){0.f, 0.f, 0.f, 0.f};
  floatx4 sacc1 = (floatx4){0.f, 0.f, 0.f, 0.f};
#pragma unroll
  for (int ks = 0; ks < 16; ++ks) {
    short8 a  = *(const short8*)(qp + ks * 512);
    short8 b0 = *(const short8*)(kp0 + ks * 512);
    sacc0 = __builtin_amdgcn_mfma_f32_16x16x32_bf16(a, b0, sacc0, 0, 0, 0);
    if (wave == 0) {
      short8 b1 = *(const short8*)(kp1 + ks * 512);
      sacc1 = __builtin_amdgcn_mfma_f32_16x16x32_bf16(a, b1, sacc1, 0, 0, 0);
    }
  }

#pragma unroll
  for (int r = 0; r < 4; ++r)
    s_s[(quad * 4 + r) * SLD + wave * 16 + mlane] = sacc0[r];
  if (wave == 0) {
#pragma unroll
    for (int r = 0; r < 4; ++r)
      s_s[(quad * 4 + r) * SLD + 64 + mlane] = sacc1[r];
  }
  __syncthreads();

  // ---- masked softmax (one 16-lane group per row) — unchanged numerics
  {
    const int row = tid >> 4, li = tid & 15;
    const float inv_scale = 0.044194173824159216f;  // 512^-0.5
    float e[5];
    float mx = -INFINITY;
#pragma unroll
    for (int i = 0; i < 5; ++i) {
      const int r = li + 16 * i;
      const int j = r - 1 - row;
      const int src = t0 - 32 + r;
      const bool valid = (j >= 0) && (j < WSZ) && (src >= 0) && (src < TT);
      e[i] = valid ? s_s[row * SLD + r] * inv_scale : -INFINITY;
      mx = fmaxf(mx, e[i]);
    }
    mx = fmaxf(mx, __shfl_xor(mx, 1)); mx = fmaxf(mx, __shfl_xor(mx, 2));
    mx = fmaxf(mx, __shfl_xor(mx, 4)); mx = fmaxf(mx, __shfl_xor(mx, 8));
    float sum = 0.f;
#pragma unroll
    for (int i = 0; i < 5; ++i) {
      e[i] = (e[i] == -INFINITY) ? 0.f : __expf(e[i] - mx);
      sum += e[i];
    }
    sum += __shfl_xor(sum, 1); sum += __shfl_xor(sum, 2);
    sum += __shfl_xor(sum, 4); sum += __shfl_xor(sum, 8);
    const float rs = 1.f / sum;
#pragma unroll
    for (int i = 0; i < 5; ++i)
      p_s[row * PLD + li + 16 * i] = bf16_rn(e[i] * rs);
    if (li < 8) {
      p_s[row * PLD + 80 + li] = 0;
      p_s[row * PLD + 88 + li] = 0;
      p_s[row * PLD + 96 + li] = 0;
    }
  }
  __syncthreads();

  // P fragments are nt-invariant: hoist the 3 LDS reads (R5 win, kept)
  short8 pa[3];
#pragma unroll
  for (int ks = 0; ks < 3; ++ks)
    pa[ks] = *(const short8*)(&p_s[mlane * PLD + ks * 32 + quad * 8]);

  // ---- PV from tiled vT; output written tiled (A-type) for gemm2
  const ptrdiff_t mp0 = ((ptrdiff_t)bt0 - 32) >> 3;  // m-packet base (global)
  const size_t ob = (size_t)tile * 8192 + (size_t)(mlane >> 3) * 128 +
                    (size_t)quad * 32 + (mlane & 7);
#pragma unroll 2
  for (int nt8 = 0; nt8 < 8; ++nt8) {
    const int nt = wave * 8 + nt8;
    const ushort* vb = VT + (ptrdiff_t)nt * 65536 + (mp0 + quad) * 128 + mlane * 8;
    floatx4 o = (floatx4){0.f, 0.f, 0.f, 0.f};
#pragma unroll
    for (int ks = 0; ks < 3; ++ks) {
      short8 bv = *(const short8*)(vb + ks * 512);
      o = __builtin_amdgcn_mfma_f32_16x16x32_bf16(pa[ks], bv, o, 0, 0, 0);
    }
#pragma unroll
    for (int r = 0; r < 4; ++r)
      outT[ob + (size_t)nt * 256 + r * 8] = bf16_rn(o[r]);
  }
}

// ---------------------------------------------------------------------------
extern "C" void kernel_launch(void* const* d_in, const int* in_sizes, int n_in,
                              void* d_out, int out_size, void* d_ws, size_t ws_size,
                              hipStream_t stream) {
  const float* x      = (const float*)d_in[0];
  const float* w_qkv  = (const float*)d_in[1];
  const float* b_qkv  = (const float*)d_in[2];
  const float* w_proj = (const float*)d_in[3];
  const float* b_proj = (const float*)d_in[4];
  float* outp = (float*)d_out;

  // ws layout (ushorts). 256KB front guard absorbs Qb/Kb negative tile reads;
  // attn_t after Kb absorbs K tile overrun; vT has 1024-elem guards both sides.
  ushort* base  = (ushort*)d_ws;
  ushort* Qb    = base + 131072;       // [256][64][16][8] = 2M elems
  ushort* Kb    = Qb + 2097152;        // same shape (gemm1 derives as C+2M)
  ushort* attnT = Kb + 2097152;        // [256][64][16][8]
  ushort* xbT   = attnT + 2097152;     // [256][64][16][8]
  ushort* wqbT  = xbT + 2097152;       // [24][64][64][8]
  ushort* wpbT  = wqbT + 786432;       // [8][64][64][8]
  ushort* vTg   = wpbT + 262144;       // guard 1024
  ushort* vT    = vTg + 1024;          // [32][512][16][8] + tail guard 1024

  // 0) convert fp32 inputs -> tiled bf16 ws buffers
  convert_bf16<<<(NX + NWQ + NWP) / (256 * 8), 256, 0, stream>>>(
      x, w_qkv, w_proj, xbT, wqbT, wpbT);
  // 1) qkv GEMM -> Q,K tiles + tiled vT (V path, no LDS transpose)
  {
    dim3 grid((3 * CC) / 64, MM / 128);  // 24 x 32 = 768 blocks
    gemm_panel<128, ushort><<<grid, 256, 0, stream>>>(
        xbT, wqbT, b_qkv, Qb, vT, 3 * CC);
  }
  // 2) banded attention, 256 blocks (1/CU), tiled in/out
  attn_mfma<<<256, 256, 0, stream>>>(Qb, Kb, vT, attnT);
  // 3) out = attn @ w_proj.T + b_proj -> fp32 row-major
  {
    dim3 grid(CC / 64, MM / 64);  // 8 x 64 = 512 blocks
    gemm_panel<64, float><<<grid, 256, 0, stream>>>(
        attnT, wpbT, b_proj, outp, nullptr, CC);
  }
}

// Round 8
// 104.536 us; speedup vs baseline: 1.0882x; 1.0738x over previous
//
#include <hip/hip_runtime.h>
#include <math.h>

// LocalAttention: B=2, T=2048, C=512, WINDOW=32
#define BB 2
#define TT 2048
#define CC 512
#define WIN 32
#define WSZ 63            // 2*WIN-1
#define MM (BB * TT)      // 4096

typedef __attribute__((ext_vector_type(8))) short short8;
typedef __attribute__((ext_vector_type(4))) float floatx4;

__device__ inline unsigned short bf16_rn(float f) {
  unsigned u = __builtin_bit_cast(unsigned, f);
  u += 0x7fff + ((u >> 16) & 1);
  return (unsigned short)(u >> 16);
}
__device__ inline unsigned pack_bf16x2(float lo, float hi) {
  return (unsigned)bf16_rn(lo) | ((unsigned)bf16_rn(hi) << 16);
}

// ---------------------------------------------------------------------------
// Pre-convert fp32 inputs -> bf16. 8 elems/thread.
// (R4 lesson: keep this stage; steady-state kernels read only ws copies.)
// R8 change (surgical, R7 post-mortem): ONLY xb gets the packet-tiled layout
//   xb[mt=m/16][kp=k/8][m&15][k&7]  (one contiguous 256B line per 16-lane
// A-fragment read in gemm1 — was 16 lines at 1KB stride). Writer cost is
// unchanged (still one 16B packet per thread, address-only change). wqb/wpb
// stay row-major (their staging/epilogue paths were the R7 regression).
// ---------------------------------------------------------------------------
#define NX  (MM * CC)          // 2097152
#define NWQ (3 * CC * CC)      // 786432
#define NWP (CC * CC)          // 262144

__global__ __launch_bounds__(256) void convert_bf16(
    const float* __restrict__ x, const float* __restrict__ wq,
    const float* __restrict__ wp, ushort* __restrict__ xb,
    ushort* __restrict__ wqb, ushort* __restrict__ wpb) {
  const size_t e = ((size_t)blockIdx.x * 256 + threadIdx.x) * 8;
  const float* src;
  ushort* dst;
  size_t off;
  if (e < NX) {
    const size_t m = e >> 9, k = e & 511;
    src = x + e; dst = xb;
    off = (m >> 4) * 8192 + (k >> 3) * 128 + (m & 15) * 8;   // A-tiled
  } else if (e < NX + NWQ) {
    src = wq; dst = wqb; off = e - NX; src += off;
  } else {
    src = wp; dst = wpb; off = e - NX - NWQ; src += off;
  }
  float4 v0 = ((const float4*)src)[0];
  float4 v1 = ((const float4*)src)[1];
  uint4 o;
  o.x = pack_bf16x2(v0.x, v0.y);
  o.y = pack_bf16x2(v0.z, v0.w);
  o.z = pack_bf16x2(v1.x, v1.y);
  o.w = pack_bf16x2(v1.z, v1.w);
  *(uint4*)(dst + off) = o;
}

// ---------------------------------------------------------------------------
// Barrier-light NT GEMM: C[m,n] = sum_k A[m,k]*B[n,k] + bias[n], K=512 fixed.
// Block = BM x 64. B-panel (64 n x 256 k) staged in LDS once per k-half ->
// only 3 barriers per block, NO per-K-step barrier/drain. A fragments are
// loaded directly from global: ATILED=true reads the packet-tiled xb (one
// 256B line per 16-lane fragment); ATILED=false reads row-major (gemm2's A).
// 4 waves, each owns BM/4 m-rows and the full 64-n range.
// V path (VT != nullptr && n0 >= 1024): tile is bias-added, packed to bf16,
// transposed through LDS, and written as coalesced 256B rows of VT[n][m].
// ---------------------------------------------------------------------------
#define PSTR 264   // B-panel k-stride (elems); 528B rows -> 2-way banked frag reads
#define VSTR 136   // V-transpose m-stride (elems); 16B-aligned rows, odd granules

template <int BM, bool ATILED, typename OT>
__global__ __launch_bounds__(256) void gemm_panel(
    const ushort* __restrict__ A, const ushort* __restrict__ B,
    const float* __restrict__ bias, OT* __restrict__ C,
    ushort* __restrict__ VT, int M, int N) {
  constexpr int MIW = BM / 64;                    // m-frags per wave (2 or 1)
  __shared__ __align__(16) ushort Bs[64 * PSTR];  // 33792 B; Vt aliases below

  const int tid = threadIdx.x;
  const int lane = tid & 63;
  const int wave = tid >> 6;
  const int m0 = blockIdx.y * BM;
  const int n0 = blockIdx.x * 64;
  const int wm = wave * (BM / 4);
  const int mlane = lane & 15, quad = lane >> 4;

  floatx4 acc[MIW][4];
#pragma unroll
  for (int i = 0; i < MIW; ++i)
#pragma unroll
    for (int j = 0; j < 4; ++j) acc[i][j] = (floatx4){0.f, 0.f, 0.f, 0.f};

  for (int h = 0; h < 2; ++h) {
    if (h) __syncthreads();
    // stage B panel half: 64 rows x 256 k = 2048 uint4, coalesced
#pragma unroll
    for (int i = 0; i < 8; ++i) {
      const int idx = tid + 256 * i;
      const int r = idx >> 5, kc = (idx & 31) * 8;
      *(uint4*)(&Bs[r * PSTR + kc]) =
          *(const uint4*)(B + (size_t)(n0 + r) * CC + h * 256 + kc);
    }
    __syncthreads();
#pragma unroll
    for (int ks = 0; ks < 8; ++ks) {
      short8 bfr[4];
#pragma unroll
      for (int ni = 0; ni < 4; ++ni)
        bfr[ni] = *(const short8*)(&Bs[(ni * 16 + mlane) * PSTR + ks * 32 + quad * 8]);
#pragma unroll
      for (int mi = 0; mi < MIW; ++mi) {
        short8 af;
        if constexpr (ATILED) {
          // xb[mt][kp][m&15][8]: mt=(m0+wm)/16+mi, kp=h*32+ks*4+quad
          af = *(const short8*)(
              A + (size_t)((m0 + wm) / 16 + mi) * 8192 +
                  (size_t)(h * 32 + ks * 4 + quad) * 128 + mlane * 8);
        } else {
          af = *(const short8*)(
              A + (size_t)(m0 + wm + mi * 16 + mlane) * CC + h * 256 + ks * 32 + quad * 8);
        }
#pragma unroll
        for (int ni = 0; ni < 4; ++ni)
          acc[mi][ni] = __builtin_amdgcn_mfma_f32_16x16x32_bf16(af, bfr[ni], acc[mi][ni], 0, 0, 0);
      }
    }
  }

  // epilogue: D row = quad*4 + r (m), col = mlane (n)
  const bool vpath = (VT != nullptr) && (n0 >= 1024);
  if (!vpath) {
#pragma unroll
    for (int ni = 0; ni < 4; ++ni) {
      const int n = n0 + ni * 16 + mlane;
      const float bn = bias[n];
#pragma unroll
      for (int mi = 0; mi < MIW; ++mi) {
        const int mbase = m0 + wm + mi * 16 + quad * 4;
#pragma unroll
        for (int r = 0; r < 4; ++r) {
          float val = acc[mi][ni][r] + bn;
          if constexpr (sizeof(OT) == 2)
            ((ushort*)C)[(size_t)(mbase + r) * N + n] = bf16_rn(val);
          else
            ((float*)C)[(size_t)(mbase + r) * N + n] = val;
        }
      }
    }
  } else if constexpr (BM == 128) {
    // transpose through LDS, then coalesced VT[n][m] row writes
    ushort* Vt = Bs;  // alias; 64 x VSTR = 17408 B
    __syncthreads();
#pragma unroll
    for (int ni = 0; ni < 4; ++ni) {
      const int n_l = ni * 16 + mlane;
      const float bn = bias[n0 + n_l];
#pragma unroll
      for (int mi = 0; mi < MIW; ++mi) {
        const int m_l = wm + mi * 16 + quad * 4;
        ushort4 pk;
        pk.x = bf16_rn(acc[mi][ni][0] + bn);
        pk.y = bf16_rn(acc[mi][ni][1] + bn);
        pk.z = bf16_rn(acc[mi][ni][2] + bn);
        pk.w = bf16_rn(acc[mi][ni][3] + bn);
        *(ushort4*)(&Vt[n_l * VSTR + m_l]) = pk;
      }
    }
    __syncthreads();
#pragma unroll
    for (int i = 0; i < 4; ++i) {  // 64 rows x 16 uint4
      const int idx = tid + 256 * i;
      const int n_l = idx >> 4, mo = (idx & 15) * 8;
      *(uint4*)(VT + (size_t)(n0 - 1024 + n_l) * M + m0 + mo) =
          *(const uint4*)(&Vt[n_l * VSTR + mo]);
    }
  }
}

// ---------------------------------------------------------------------------
// LDS-free MFMA banded attention (R5 version, unchanged). Block = 16 tokens,
// grid 256 = 1 block/CU (R6 lesson: keep all CUs, short per-block path),
// XCD-bijective swizzle -> contiguous 512-token span per XCD.
// OOB reads fault-safe via ws guards; garbage lands in masked/P=0 positions.
// ---------------------------------------------------------------------------
#define ATILE 16
#define SLD 84    // S row stride (floats)
#define PLD 104   // P row stride (ushorts), odd granules -> conflict-free

__global__ __launch_bounds__(256) void attn_mfma(
    const ushort* __restrict__ qkv, const ushort* __restrict__ vT,
    ushort* __restrict__ out) {
  __shared__ __align__(16) float s_s[16 * SLD];
  __shared__ __align__(16) ushort p_s[16 * PLD];

  const int tid = threadIdx.x;
  const int wave = tid >> 6, lane = tid & 63;
  const int mlane = lane & 15, quad = lane >> 4;
  // XCD-bijective swizzle: 256 blocks, 8 XCDs, 32 tiles each (contiguous)
  const int tile = ((blockIdx.x & 7) << 5) | (blockIdx.x >> 3);
  const int bt0 = tile * ATILE;
  const int b = bt0 / TT, t0 = bt0 % TT;
  const ushort* qbase = qkv + (size_t)b * TT * (3 * CC);

  const ushort* qrow  = qbase + (ptrdiff_t)(t0 + mlane) * (3 * CC);
  const ushort* krow0 = qbase + (ptrdiff_t)(t0 - 32 + wave * 16 + mlane) * (3 * CC) + CC;
  const ushort* krow1 = qbase + (ptrdiff_t)(t0 - 32 + 64 + mlane) * (3 * CC) + CC;
  floatx4 sacc0 = (floatx4){0.f, 0.f, 0.f, 0.f};
  floatx4 sacc1 = (floatx4){0.f, 0.f, 0.f, 0.f};
#pragma unroll
  for (int ks = 0; ks < 16; ++ks) {
    short8 a  = *(const short8*)(qrow + ks * 32 + quad * 8);
    short8 b0 = *(const short8*)(krow0 + ks * 32 + quad * 8);
    sacc0 = __builtin_amdgcn_mfma_f32_16x16x32_bf16(a, b0, sacc0, 0, 0, 0);
    if (wave == 0) {
      short8 b1 = *(const short8*)(krow1 + ks * 32 + quad * 8);
      sacc1 = __builtin_amdgcn_mfma_f32_16x16x32_bf16(a, b1, sacc1, 0, 0, 0);
    }
  }

#pragma unroll
  for (int r = 0; r < 4; ++r)
    s_s[(quad * 4 + r) * SLD + wave * 16 + mlane] = sacc0[r];
  if (wave == 0) {
#pragma unroll
    for (int r = 0; r < 4; ++r)
      s_s[(quad * 4 + r) * SLD + 64 + mlane] = sacc1[r];
  }
  __syncthreads();

  {
    const int row = tid >> 4, li = tid & 15;
    const float inv_scale = 0.044194173824159216f;  // 512^-0.5
    float e[5];
    float mx = -INFINITY;
#pragma unroll
    for (int i = 0; i < 5; ++i) {
      const int r = li + 16 * i;
      const int j = r - 1 - row;
      const int src = t0 - 32 + r;
      const bool valid = (j >= 0) && (j < WSZ) && (src >= 0) && (src < TT);
      e[i] = valid ? s_s[row * SLD + r] * inv_scale : -INFINITY;
      mx = fmaxf(mx, e[i]);
    }
    mx = fmaxf(mx, __shfl_xor(mx, 1)); mx = fmaxf(mx, __shfl_xor(mx, 2));
    mx = fmaxf(mx, __shfl_xor(mx, 4)); mx = fmaxf(mx, __shfl_xor(mx, 8));
    float sum = 0.f;
#pragma unroll
    for (int i = 0; i < 5; ++i) {
      e[i] = (e[i] == -INFINITY) ? 0.f : __expf(e[i] - mx);
      sum += e[i];
    }
    sum += __shfl_xor(sum, 1); sum += __shfl_xor(sum, 2);
    sum += __shfl_xor(sum, 4); sum += __shfl_xor(sum, 8);
    const float rs = 1.f / sum;
#pragma unroll
    for (int i = 0; i < 5; ++i)
      p_s[row * PLD + li + 16 * i] = bf16_rn(e[i] * rs);
    if (li < 8) {
      p_s[row * PLD + 80 + li] = 0;
      p_s[row * PLD + 88 + li] = 0;
      p_s[row * PLD + 96 + li] = 0;
    }
  }
  __syncthreads();

  // P fragments are nt8-invariant: hoist the 3 LDS reads out of the PV loop.
  short8 pa[3];
#pragma unroll
  for (int ks = 0; ks < 3; ++ks)
    pa[ks] = *(const short8*)(&p_s[mlane * PLD + ks * 32 + quad * 8]);

  const ptrdiff_t mcol0 = (ptrdiff_t)b * TT + t0 - 32;
#pragma unroll 2
  for (int nt8 = 0; nt8 < 8; ++nt8) {
    const int nt = wave * 8 + nt8;
    const ushort* vrow = vT + (ptrdiff_t)(nt * 16 + mlane) * MM + mcol0;
    floatx4 o = (floatx4){0.f, 0.f, 0.f, 0.f};
#pragma unroll
    for (int ks = 0; ks < 3; ++ks) {
      short8 bv = *(const short8*)(vrow + ks * 32 + quad * 8);
      o = __builtin_amdgcn_mfma_f32_16x16x32_bf16(pa[ks], bv, o, 0, 0, 0);
    }
#pragma unroll
    for (int r = 0; r < 4; ++r)
      out[(size_t)(bt0 + quad * 4 + r) * CC + nt * 16 + mlane] = bf16_rn(o[r]);
  }
}

// ---------------------------------------------------------------------------
extern "C" void kernel_launch(void* const* d_in, const int* in_sizes, int n_in,
                              void* d_out, int out_size, void* d_ws, size_t ws_size,
                              hipStream_t stream) {
  const float* x      = (const float*)d_in[0];
  const float* w_qkv  = (const float*)d_in[1];
  const float* b_qkv  = (const float*)d_in[2];
  const float* w_proj = (const float*)d_in[3];
  const float* b_proj = (const float*)d_in[4];
  float* outp = (float*)d_out;

  // ws layout (ushorts). 256 KB front guard absorbs attn's src<0 K-reads;
  // attn buffer right after qkv absorbs src>=TT K-read overruns.
  ushort* base  = (ushort*)d_ws;
  ushort* qkv   = base + 131072;                   // MM x 1536 (V third unused)
  ushort* attn  = qkv + (size_t)MM * 3 * CC;       // MM x 512
  ushort* xb    = attn + (size_t)MM * CC;          // MM x 512 (A-tiled)
  ushort* wqb   = xb + (size_t)NX;                 // 1536 x 512
  ushort* wpb   = wqb + (size_t)NWQ;               // 512 x 512
  ushort* vTg   = wpb + (size_t)NWP;               // guard(64) + 512 x 4096 + guard(64)
  ushort* vT    = vTg + 64;

  // 0) convert fp32 inputs to bf16 (xb packet-tiled; weights row-major)
  convert_bf16<<<(NX + NWQ + NWP) / (256 * 8), 256, 0, stream>>>(x, w_qkv, w_proj, xb, wqb, wpb);
  // 1) qkv = x @ w_qkv.T + b_qkv -> Q,K bf16 rows; V written transposed to vT
  {
    dim3 grid((3 * CC) / 64, MM / 128);  // 24 x 32 = 768 blocks
    gemm_panel<128, true, ushort><<<grid, 256, 0, stream>>>(xb, wqb, b_qkv, qkv, vT, MM, 3 * CC);
  }
  // 2) banded attention (bf16 -> bf16), LDS-free MFMA, 256 blocks (1/CU)
  attn_mfma<<<MM / ATILE, 256, 0, stream>>>(qkv, vT, attn);
  // 3) out = attn @ w_proj.T + b_proj -> fp32
  {
    dim3 grid(CC / 64, MM / 64);  // 8 x 64 = 512 blocks
    gemm_panel<64, false, float><<<grid, 256, 0, stream>>>(attn, wpb, b_proj, outp, nullptr, MM, CC);
  }
}

// Round 9
// 104.402 us; speedup vs baseline: 1.0896x; 1.0013x over previous
//
#include <hip/hip_runtime.h>
#include <math.h>

// LocalAttention: B=2, T=2048, C=512, WINDOW=32
#define BB 2
#define TT 2048
#define CC 512
#define WIN 32
#define WSZ 63            // 2*WIN-1
#define MM (BB * TT)      // 4096

typedef __attribute__((ext_vector_type(8))) short short8;
typedef __attribute__((ext_vector_type(4))) float floatx4;

__device__ inline unsigned short bf16_rn(float f) {
  unsigned u = __builtin_bit_cast(unsigned, f);
  u += 0x7fff + ((u >> 16) & 1);
  return (unsigned short)(u >> 16);
}
__device__ inline unsigned pack_bf16x2(float lo, float hi) {
  return (unsigned)bf16_rn(lo) | ((unsigned)bf16_rn(hi) << 16);
}

// ---------------------------------------------------------------------------
// Pre-convert fp32 inputs -> bf16. 8 elems/thread.
// (R4 lesson: keep this stage; steady-state kernels read only ws copies.)
// xb is packet-tiled [mt=m/16][kp=k/8][m&15][k&7] (R8 win: one 256B line per
// 16-lane A-fragment read in gemm1). Weights stay row-major (R7 lesson).
// ---------------------------------------------------------------------------
#define NX  (MM * CC)          // 2097152
#define NWQ (3 * CC * CC)      // 786432
#define NWP (CC * CC)          // 262144

__global__ __launch_bounds__(256) void convert_bf16(
    const float* __restrict__ x, const float* __restrict__ wq,
    const float* __restrict__ wp, ushort* __restrict__ xb,
    ushort* __restrict__ wqb, ushort* __restrict__ wpb) {
  const size_t e = ((size_t)blockIdx.x * 256 + threadIdx.x) * 8;
  const float* src;
  ushort* dst;
  size_t off;
  if (e < NX) {
    const size_t m = e >> 9, k = e & 511;
    src = x + e; dst = xb;
    off = (m >> 4) * 8192 + (k >> 3) * 128 + (m & 15) * 8;   // A-tiled
  } else if (e < NX + NWQ) {
    src = wq; dst = wqb; off = e - NX; src += off;
  } else {
    src = wp; dst = wpb; off = e - NX - NWQ; src += off;
  }
  float4 v0 = ((const float4*)src)[0];
  float4 v1 = ((const float4*)src)[1];
  uint4 o;
  o.x = pack_bf16x2(v0.x, v0.y);
  o.y = pack_bf16x2(v0.z, v0.w);
  o.z = pack_bf16x2(v1.x, v1.y);
  o.w = pack_bf16x2(v1.z, v1.w);
  *(uint4*)(dst + off) = o;
}

// ---------------------------------------------------------------------------
// Barrier-light NT GEMM: C[m,n] = sum_k A[m,k]*B[n,k] + bias[n], K=512 fixed.
// Block = BM x 64. B-panel staged in LDS once per k-half, 3 barriers total.
// ATILED: A fragments from packet-tiled xb (1 line / 16-lane group).
// QKT (gemm1): Q (n<512) and K (512..1023) epilogues write packet-tiled
//   Qb/Kb (same 32 scalar stores per thread, tiled addresses; 16-lane group
//   = 2x16B contiguous chunks, same coalescing as old row-major writes) so
//   attn's fragment reads are 1 line instead of 16 (R9 change).
//   V path (n0>=1024): UNCHANGED R5 LDS-transpose + coalesced vT row writes.
// ---------------------------------------------------------------------------
#define PSTR 264   // B-panel k-stride (elems); 528B rows -> 2-way banked frag reads
#define VSTR 136   // V-transpose m-stride (elems); 16B-aligned rows, odd granules

template <int BM, bool ATILED, bool QKT, typename OT>
__global__ __launch_bounds__(256) void gemm_panel(
    const ushort* __restrict__ A, const ushort* __restrict__ B,
    const float* __restrict__ bias, OT* __restrict__ C,
    ushort* __restrict__ VT, int M, int N) {
  constexpr int MIW = BM / 64;                    // m-frags per wave (2 or 1)
  __shared__ __align__(16) ushort Bs[64 * PSTR];  // 33792 B; Vt aliases below

  const int tid = threadIdx.x;
  const int lane = tid & 63;
  const int wave = tid >> 6;
  const int m0 = blockIdx.y * BM;
  const int n0 = blockIdx.x * 64;
  const int wm = wave * (BM / 4);
  const int mlane = lane & 15, quad = lane >> 4;

  floatx4 acc[MIW][4];
#pragma unroll
  for (int i = 0; i < MIW; ++i)
#pragma unroll
    for (int j = 0; j < 4; ++j) acc[i][j] = (floatx4){0.f, 0.f, 0.f, 0.f};

  for (int h = 0; h < 2; ++h) {
    if (h) __syncthreads();
    // stage B panel half: 64 rows x 256 k = 2048 uint4, coalesced
#pragma unroll
    for (int i = 0; i < 8; ++i) {
      const int idx = tid + 256 * i;
      const int r = idx >> 5, kc = (idx & 31) * 8;
      *(uint4*)(&Bs[r * PSTR + kc]) =
          *(const uint4*)(B + (size_t)(n0 + r) * CC + h * 256 + kc);
    }
    __syncthreads();
#pragma unroll
    for (int ks = 0; ks < 8; ++ks) {
      short8 bfr[4];
#pragma unroll
      for (int ni = 0; ni < 4; ++ni)
        bfr[ni] = *(const short8*)(&Bs[(ni * 16 + mlane) * PSTR + ks * 32 + quad * 8]);
#pragma unroll
      for (int mi = 0; mi < MIW; ++mi) {
        short8 af;
        if constexpr (ATILED) {
          // xb[mt][kp][m&15][8]: mt=(m0+wm)/16+mi, kp=h*32+ks*4+quad
          af = *(const short8*)(
              A + (size_t)((m0 + wm) / 16 + mi) * 8192 +
                  (size_t)(h * 32 + ks * 4 + quad) * 128 + mlane * 8);
        } else {
          af = *(const short8*)(
              A + (size_t)(m0 + wm + mi * 16 + mlane) * CC + h * 256 + ks * 32 + quad * 8);
        }
#pragma unroll
        for (int ni = 0; ni < 4; ++ni)
          acc[mi][ni] = __builtin_amdgcn_mfma_f32_16x16x32_bf16(af, bfr[ni], acc[mi][ni], 0, 0, 0);
      }
    }
  }

  // epilogue: D row = quad*4 + r (m), col = mlane (n)
  if constexpr (QKT) {
    if (n0 < 1024) {
      // Q (n<512) / K (512..1023): packet-tiled A-type writes
      ushort* dst = (ushort*)C + (n0 < 512 ? 0 : 2097152);
      const int c0 = n0 & 511;
#pragma unroll
      for (int ni = 0; ni < 4; ++ni) {
        const int c = c0 + ni * 16 + mlane;
        const float bn = bias[n0 + ni * 16 + mlane];
        const int kpo = (c >> 3) * 128 + (c & 7);
#pragma unroll
        for (int mi = 0; mi < MIW; ++mi) {
          const size_t mb =
              (size_t)((m0 + wm) / 16 + mi) * 8192 + kpo + (size_t)quad * 32;
#pragma unroll
          for (int r = 0; r < 4; ++r)
            dst[mb + r * 8] = bf16_rn(acc[mi][ni][r] + bn);
        }
      }
    } else if constexpr (BM == 128) {
      // V: transpose through LDS, then coalesced VT[n][m] row writes (R5)
      ushort* Vt = Bs;  // alias; 64 x VSTR = 17408 B
      __syncthreads();
#pragma unroll
      for (int ni = 0; ni < 4; ++ni) {
        const int n_l = ni * 16 + mlane;
        const float bn = bias[n0 + n_l];
#pragma unroll
        for (int mi = 0; mi < MIW; ++mi) {
          const int m_l = wm + mi * 16 + quad * 4;
          ushort4 pk;
          pk.x = bf16_rn(acc[mi][ni][0] + bn);
          pk.y = bf16_rn(acc[mi][ni][1] + bn);
          pk.z = bf16_rn(acc[mi][ni][2] + bn);
          pk.w = bf16_rn(acc[mi][ni][3] + bn);
          *(ushort4*)(&Vt[n_l * VSTR + m_l]) = pk;
        }
      }
      __syncthreads();
#pragma unroll
      for (int i = 0; i < 4; ++i) {  // 64 rows x 16 uint4
        const int idx = tid + 256 * i;
        const int n_l = idx >> 4, mo = (idx & 15) * 8;
        *(uint4*)(VT + (size_t)(n0 - 1024 + n_l) * M + m0 + mo) =
            *(const uint4*)(&Vt[n_l * VSTR + mo]);
      }
    }
  } else {
    // row-major epilogue (gemm2: fp32 final out)
#pragma unroll
    for (int ni = 0; ni < 4; ++ni) {
      const int n = n0 + ni * 16 + mlane;
      const float bn = bias[n];
#pragma unroll
      for (int mi = 0; mi < MIW; ++mi) {
        const int mbase = m0 + wm + mi * 16 + quad * 4;
#pragma unroll
        for (int r = 0; r < 4; ++r) {
          float val = acc[mi][ni][r] + bn;
          if constexpr (sizeof(OT) == 2)
            ((ushort*)C)[(size_t)(mbase + r) * N + n] = bf16_rn(val);
          else
            ((float*)C)[(size_t)(mbase + r) * N + n] = val;
        }
      }
    }
  }
}

// ---------------------------------------------------------------------------
// LDS-free MFMA banded attention. Block = 16 tokens, grid 256 = 1 block/CU
// (R6 lesson), XCD-bijective swizzle. R9: Q/K fragment loads now hit the
// packet-tiled Qb/Kb — one contiguous 256B region per 16-lane group (1 line,
// was 16 at 6KB stride). PV path (vT row-major reads) and output writes are
// byte-identical to R8. Kb tile-underrun lands in Qb tail, overrun in the
// attn buffer placed right after Kb — garbage in masked positions.
// ---------------------------------------------------------------------------
#define ATILE 16
#define SLD 84    // S row stride (floats)
#define PLD 104   // P row stride (ushorts), odd granules -> conflict-free

__global__ __launch_bounds__(256) void attn_mfma(
    const ushort* __restrict__ Qb, const ushort* __restrict__ Kb,
    const ushort* __restrict__ vT, ushort* __restrict__ out) {
  __shared__ __align__(16) float s_s[16 * SLD];
  __shared__ __align__(16) ushort p_s[16 * PLD];

  const int tid = threadIdx.x;
  const int wave = tid >> 6, lane = tid & 63;
  const int mlane = lane & 15, quad = lane >> 4;
  // XCD-bijective swizzle: 256 blocks, 8 XCDs, 32 tiles each (contiguous)
  const int tile = ((blockIdx.x & 7) << 5) | (blockIdx.x >> 3);
  const int bt0 = tile * ATILE;
  const int b = bt0 / TT, t0 = bt0 % TT;

  // ---- QK^T over the 80-key band (key tiles tile-2 .. tile+2)
  const ushort* qp  = Qb + (size_t)tile * 8192 + quad * 128 + mlane * 8;
  const ushort* kp0 = Kb + (ptrdiff_t)(tile - 2 + wave) * 8192 + quad * 128 + mlane * 8;
  const ushort* kp1 = Kb + (ptrdiff_t)(tile + 2) * 8192 + quad * 128 + mlane * 8;
  floatx4 sacc0 = (floatx4){0.f, 0.f, 0.f, 0.f};
  floatx4 sacc1 = (floatx4){0.f, 0.f, 0.f, 0.f};
#pragma unroll
  for (int ks = 0; ks < 16; ++ks) {
    short8 a  = *(const short8*)(qp + ks * 512);
    short8 b0 = *(const short8*)(kp0 + ks * 512);
    sacc0 = __builtin_amdgcn_mfma_f32_16x16x32_bf16(a, b0, sacc0, 0, 0, 0);
    if (wave == 0) {
      short8 b1 = *(const short8*)(kp1 + ks * 512);
      sacc1 = __builtin_amdgcn_mfma_f32_16x16x32_bf16(a, b1, sacc1, 0, 0, 0);
    }
  }

#pragma unroll
  for (int r = 0; r < 4; ++r)
    s_s[(quad * 4 + r) * SLD + wave * 16 + mlane] = sacc0[r];
  if (wave == 0) {
#pragma unroll
    for (int r = 0; r < 4; ++r)
      s_s[(quad * 4 + r) * SLD + 64 + mlane] = sacc1[r];
  }
  __syncthreads();

  {
    const int row = tid >> 4, li = tid & 15;
    const float inv_scale = 0.044194173824159216f;  // 512^-0.5
    float e[5];
    float mx = -INFINITY;
#pragma unroll
    for (int i = 0; i < 5; ++i) {
      const int r = li + 16 * i;
      const int j = r - 1 - row;
      const int src = t0 - 32 + r;
      const bool valid = (j >= 0) && (j < WSZ) && (src >= 0) && (src < TT);
      e[i] = valid ? s_s[row * SLD + r] * inv_scale : -INFINITY;
      mx = fmaxf(mx, e[i]);
    }
    mx = fmaxf(mx, __shfl_xor(mx, 1)); mx = fmaxf(mx, __shfl_xor(mx, 2));
    mx = fmaxf(mx, __shfl_xor(mx, 4)); mx = fmaxf(mx, __shfl_xor(mx, 8));
    float sum = 0.f;
#pragma unroll
    for (int i = 0; i < 5; ++i) {
      e[i] = (e[i] == -INFINITY) ? 0.f : __expf(e[i] - mx);
      sum += e[i];
    }
    sum += __shfl_xor(sum, 1); sum += __shfl_xor(sum, 2);
    sum += __shfl_xor(sum, 4); sum += __shfl_xor(sum, 8);
    const float rs = 1.f / sum;
#pragma unroll
    for (int i = 0; i < 5; ++i)
      p_s[row * PLD + li + 16 * i] = bf16_rn(e[i] * rs);
    if (li < 8) {
      p_s[row * PLD + 80 + li] = 0;
      p_s[row * PLD + 88 + li] = 0;
      p_s[row * PLD + 96 + li] = 0;
    }
  }
  __syncthreads();

  // P fragments are nt8-invariant: hoist the 3 LDS reads out of the PV loop.
  short8 pa[3];
#pragma unroll
  for (int ks = 0; ks < 3; ++ks)
    pa[ks] = *(const short8*)(&p_s[mlane * PLD + ks * 32 + quad * 8]);

  const ptrdiff_t mcol0 = (ptrdiff_t)b * TT + t0 - 32;
#pragma unroll 2
  for (int nt8 = 0; nt8 < 8; ++nt8) {
    const int nt = wave * 8 + nt8;
    const ushort* vrow = vT + (ptrdiff_t)(nt * 16 + mlane) * MM + mcol0;
    floatx4 o = (floatx4){0.f, 0.f, 0.f, 0.f};
#pragma unroll
    for (int ks = 0; ks < 3; ++ks) {
      short8 bv = *(const short8*)(vrow + ks * 32 + quad * 8);
      o = __builtin_amdgcn_mfma_f32_16x16x32_bf16(pa[ks], bv, o, 0, 0, 0);
    }
#pragma unroll
    for (int r = 0; r < 4; ++r)
      out[(size_t)(bt0 + quad * 4 + r) * CC + nt * 16 + mlane] = bf16_rn(o[r]);
  }
}

// ---------------------------------------------------------------------------
extern "C" void kernel_launch(void* const* d_in, const int* in_sizes, int n_in,
                              void* d_out, int out_size, void* d_ws, size_t ws_size,
                              hipStream_t stream) {
  const float* x      = (const float*)d_in[0];
  const float* w_qkv  = (const float*)d_in[1];
  const float* b_qkv  = (const float*)d_in[2];
  const float* w_proj = (const float*)d_in[3];
  const float* b_proj = (const float*)d_in[4];
  float* outp = (float*)d_out;

  // ws layout (ushorts). Kb tile-underrun (tile<2) reads Qb tail; overrun
  // (tile>253) reads the attn buffer placed right after Kb — masked garbage.
  ushort* base  = (ushort*)d_ws;
  ushort* Qb    = base + 131072;       // [256][64][16][8] = 2M
  ushort* Kb    = Qb + 2097152;        // [256][64][16][8] = 2M (C + 2M in gemm1)
  ushort* attn  = Kb + 2097152;        // MM x 512 row-major (Kb tail guard)
  ushort* xb    = attn + 2097152;      // A-tiled, 2M
  ushort* wqb   = xb + (size_t)NX;     // 1536 x 512 row-major
  ushort* wpb   = wqb + (size_t)NWQ;   // 512 x 512 row-major
  ushort* vTg   = wpb + (size_t)NWP;   // guard(64) + 512 x 4096 + guard(64)
  ushort* vT    = vTg + 64;

  // 0) convert fp32 inputs to bf16 (xb packet-tiled; weights row-major)
  convert_bf16<<<(NX + NWQ + NWP) / (256 * 8), 256, 0, stream>>>(x, w_qkv, w_proj, xb, wqb, wpb);
  // 1) qkv GEMM -> packet-tiled Qb/Kb + coalesced vT (V via LDS transpose)
  {
    dim3 grid((3 * CC) / 64, MM / 128);  // 24 x 32 = 768 blocks
    gemm_panel<128, true, true, ushort><<<grid, 256, 0, stream>>>(
        xb, wqb, b_qkv, Qb, vT, MM, 3 * CC);
  }
  // 2) banded attention (tiled Q/K reads, row-major vT/out), 256 blocks
  attn_mfma<<<MM / ATILE, 256, 0, stream>>>(Qb, Kb, vT, attn);
  // 3) out = attn @ w_proj.T + b_proj -> fp32 row-major
  {
    dim3 grid(CC / 64, MM / 64);  // 8 x 64 = 512 blocks
    gemm_panel<64, false, false, float><<<grid, 256, 0, stream>>>(
        attn, wpb, b_proj, outp, nullptr, MM, CC);
  }
}